// Round 16
// baseline (27.859 us; speedup 1.0000x reference)
//
#include <hip/hip_runtime.h>

#define NCLS 24
#define NB 8
#define NCH 128
#define WLO 128
#define WHI 512
#define CELLS (128*128)
#define BPB 128                     // blocks per batch (1 cell-row each)
#define NBLK (NB * BPB)             // 1024
#define KCH (NCLS * NCH)            // 3072
#define NF (NB * KCH)               // 24576

typedef _Float16 f16x4 __attribute__((ext_vector_type(4)));
typedef _Float16 f16x8 __attribute__((ext_vector_type(8)));
typedef float    f32x4 __attribute__((ext_vector_type(4)));
typedef int      i32x4 __attribute__((ext_vector_type(4)));

#define HSWZ(c_, e_) ((e_) ^ (((c_) & 7) << 3))

__device__ __forceinline__ void barrier_nodrain() {
    asm volatile("s_waitcnt lgkmcnt(0)" ::: "memory");
    __builtin_amdgcn_s_barrier();
}
#define VMWAIT(N) do { asm volatile("s_waitcnt vmcnt(" #N ")" ::: "memory"); \
                       __builtin_amdgcn_sched_barrier(0); } while (0)

// Compiler-opaque loads (cannot be sunk/serialized); we manage vmcnt.
__device__ __forceinline__ f32x4 gload_f4(const float* p) {
    f32x4 r;
    asm volatile("global_load_dwordx4 %0, %1, off" : "=v"(r) : "v"(p));
    return r;
}
__device__ __forceinline__ i32x4 gload_i4(const int* p) {
    i32x4 r;
    asm volatile("global_load_dwordx4 %0, %1, off" : "=v"(r) : "v"(p));
    return r;
}

// Block = one 128-cell row. ONE load storm at t=0: 2 label int4 + 16 data
// loads, each data instr = 2 channels x 512 B CONTIGUOUS (vs 4x256B before).
// Both 64-cell subtile tiles staged together; consume 0 then 1; acc in regs.
__global__ __launch_bounds__(256, 4)
void fm_main(const float* __restrict__ data, const int* __restrict__ label,
             _Float16* __restrict__ part, float* __restrict__ cpart)
{
    __shared__ float    histf[32 * 64];       // 8 KB, rows 24-31 stay zero
    __shared__ _Float16 tile[2][NCH * 64];    // 2 x 16 KB, [s][ch][cell swz]

    const int bid  = blockIdx.x;
    const int b    = bid >> 7;
    const int grp  = bid & 127;               // cell row
    const int tid  = threadIdx.x;

    const int cl   = tid & 63;        // label/hist cell
    const int w    = tid >> 6;        // wave id (= label hi-res row)
    const int lane = tid & 63;
    const int l15  = lane & 15, lg = lane >> 4;

    const float* dbase = data  + (size_t)b * NCH * CELLS + grp * WLO;
    const int*   lbase = label + (size_t)b * (WHI * WHI) + (size_t)(4 * grp + w) * WHI;

    // ---- the storm: labels first (oldest), then 16 x 512B-granule data ----
    const i32x4 lv0 = gload_i4(lbase + cl * 4);          // subtile-0 labels
    const i32x4 lv1 = gload_i4(lbase + 256 + cl * 4);    // subtile-1 labels
    f32x4 v[16];
    const int lc = (lane & 31) * 4;           // cell 0..124 within the 128-row
#pragma unroll
    for (int k = 0; k < 16; ++k) {
        const int ch = w * 32 + k * 2 + (lane >> 5);     // 2 channels / instr
        v[k] = gload_f4(dbase + (size_t)ch * CELLS + lc);
    }
    __builtin_amdgcn_sched_barrier(0);

    f32x4 acc[2][2];
#pragma unroll
    for (int mt = 0; mt < 2; ++mt)
#pragma unroll
        for (int nt = 0; nt < 2; ++nt) acc[mt][nt] = (f32x4){0.f, 0.f, 0.f, 0.f};
    float cs0 = 0.f, cs1 = 0.f;

    // ---- zero hist for subtile 0 ----
#pragma unroll
    for (int k = 0; k < 8; ++k) histf[tid + k * 256] = 0.f;
    barrier_nodrain();

    VMWAIT(16);                               // labels landed, data flying
    if ((unsigned)lv0[0] < 24u) atomicAdd(&histf[lv0[0] * 64 + HSWZ(lv0[0], cl)], 1.f);
    if ((unsigned)lv0[1] < 24u) atomicAdd(&histf[lv0[1] * 64 + HSWZ(lv0[1], cl)], 1.f);
    if ((unsigned)lv0[2] < 24u) atomicAdd(&histf[lv0[2] * 64 + HSWZ(lv0[2], cl)], 1.f);
    if ((unsigned)lv0[3] < 24u) atomicAdd(&histf[lv0[3] * 64 + HSWZ(lv0[3], cl)], 1.f);

    VMWAIT(0);                                // all data landed
    // ---- stage BOTH subtile tiles: lane's 4 cells live in one subtile ----
    {
        const int s = (lane >> 4) & 1;        // subtile of this lane's cells
        const int q = lane & 15;              // float4 slot within subtile
#pragma unroll
        for (int k = 0; k < 16; ++k) {
            const int ch = w * 32 + k * 2 + (lane >> 5);
            f16x4 hv;
            hv[0] = (_Float16)v[k][0]; hv[1] = (_Float16)v[k][1];
            hv[2] = (_Float16)v[k][2]; hv[3] = (_Float16)v[k][3];
            const int idx = ch * 64 + ((((q >> 1) ^ (ch & 7)) << 3) | ((q & 1) << 2));
            *reinterpret_cast<f16x4*>(&tile[s][idx]) = hv;
        }
    }
    barrier_nodrain();                        // hist-0 + both tiles visible

#pragma unroll
    for (int s = 0; s < 2; ++s) {
        // ---- A fragments + count partials ----
        f16x8 af[2][2];
#pragma unroll
        for (int mt = 0; mt < 2; ++mt)
#pragma unroll
            for (int kt = 0; kt < 2; ++kt) {
                const int cls = mt * 16 + l15;
                const int e0  = kt * 32 + lg * 8;
                const float* hp = &histf[cls * 64 + HSWZ(cls, e0)];
                const f32x4 h0 = *reinterpret_cast<const f32x4*>(hp);
                const f32x4 h1 = *reinterpret_cast<const f32x4*>(hp + 4);
                f16x8 a;
                a[0] = (_Float16)h0[0]; a[1] = (_Float16)h0[1]; a[2] = (_Float16)h0[2]; a[3] = (_Float16)h0[3];
                a[4] = (_Float16)h1[0]; a[5] = (_Float16)h1[1]; a[6] = (_Float16)h1[2]; a[7] = (_Float16)h1[3];
                af[mt][kt] = a;
                const float p = (h0[0] + h0[1]) + (h0[2] + h0[3]) + (h1[0] + h1[1]) + (h1[2] + h1[3]);
                if (mt == 0) cs0 += p; else cs1 += p;
            }

        // ---- B fragments from tile[s] ----
        f16x8 bf[2][2];
#pragma unroll
        for (int nt = 0; nt < 2; ++nt)
#pragma unroll
            for (int kt = 0; kt < 2; ++kt) {
                const int row = w * 32 + nt * 16 + l15;
                const int g   = kt * 4 + lg;
                bf[nt][kt] = *reinterpret_cast<const f16x8*>(&tile[s][row * 64 + ((g ^ (row & 7)) << 3)]);
            }

        // ---- 8 MFMAs, accumulate across subtiles ----
#pragma unroll
        for (int mt = 0; mt < 2; ++mt)
#pragma unroll
            for (int nt = 0; nt < 2; ++nt)
#pragma unroll
                for (int kt = 0; kt < 2; ++kt)
                    acc[mt][nt] = __builtin_amdgcn_mfma_f32_16x16x32_f16(
                        af[mt][kt], bf[nt][kt], acc[mt][nt], 0, 0, 0);

        if (s == 0) {
            barrier_nodrain();                // hist-0 reads retired
#pragma unroll
            for (int k = 0; k < 8; ++k) histf[tid + k * 256] = 0.f;
            barrier_nodrain();
            if ((unsigned)lv1[0] < 24u) atomicAdd(&histf[lv1[0] * 64 + HSWZ(lv1[0], cl)], 1.f);
            if ((unsigned)lv1[1] < 24u) atomicAdd(&histf[lv1[1] * 64 + HSWZ(lv1[1], cl)], 1.f);
            if ((unsigned)lv1[2] < 24u) atomicAdd(&histf[lv1[2] * 64 + HSWZ(lv1[2], cl)], 1.f);
            if ((unsigned)lv1[3] < 24u) atomicAdd(&histf[lv1[3] * 64 + HSWZ(lv1[3], cl)], 1.f);
            barrier_nodrain();                // hist-1 ready (tile[1] untouched)
        }
    }

    // ---- counts: butterfly over 4 k-groups; wave 0 lanes write ----
    cs0 += __shfl_xor(cs0, 16, 64); cs0 += __shfl_xor(cs0, 32, 64);
    cs1 += __shfl_xor(cs1, 16, 64); cs1 += __shfl_xor(cs1, 32, 64);
    if (w == 0 && lane < 16) {
        cpart[(size_t)bid * NCLS + lane] = cs0;
        if (lane < 8) cpart[(size_t)bid * NCLS + 16 + lane] = cs1;
    }

    // ---- flush f16 per-block partials (non-atomic) ----
    _Float16* pblk = part + (size_t)bid * KCH;
#pragma unroll
    for (int mt = 0; mt < 2; ++mt)
#pragma unroll
        for (int nt = 0; nt < 2; ++nt)
#pragma unroll
            for (int rg = 0; rg < 4; ++rg) {
                const int cls = mt * 16 + lg * 4 + rg;    // C/D: row=(lane>>4)*4+reg
                const int ch  = w * 32 + nt * 16 + l15;   //      col=lane&15
                if (cls < NCLS) pblk[cls * NCH + ch] = (_Float16)acc[mt][nt][rg];
            }
}

// Grid 384 = (b, cls, ch-half). 4 waves reduce 32 g's each -> LDS -> wave-0 finish.
__global__ __launch_bounds__(256)
void fm_final(const _Float16* __restrict__ part, const float* __restrict__ cpart,
              float* __restrict__ out)
{
    __shared__ float red[256];
    __shared__ float credv[128];
    const int bid  = blockIdx.x;
    const int b    = bid / (NCLS * 2);
    const int rem  = bid % (NCLS * 2);
    const int cls  = rem >> 1;
    const int half = rem & 1;
    const int t    = threadIdx.x;
    const int c    = t & 63;
    const int gq   = t >> 6;

    if (t < 128) credv[t] = cpart[(size_t)(b * BPB + t) * NCLS + cls];

    const _Float16* pb = part + (size_t)(b * BPB + gq * 32) * KCH + cls * NCH + half * 64 + c;
    float s = 0.f;
#pragma unroll 8
    for (int g = 0; g < 32; ++g) s += (float)pb[(size_t)g * KCH];
    red[t] = s;
    __syncthreads();

    if (t < 64) {
        float cnt = credv[t] + credv[t + 64];
#pragma unroll
        for (int o = 32; o >= 1; o >>= 1) cnt += __shfl_xor(cnt, o, 64);
        const float sf = red[t] + red[t + 64] + red[t + 128] + red[t + 192];
        out[(size_t)b * KCH + (half * 64 + t) * NCLS + cls] = sf / (cnt + 1e-8f);  // (B,C,NCLS)
        if (t == 0 && half == 0) out[NF + b * NCLS + cls] = (cnt > 0.f) ? 1.f : 0.f;
    }
}

extern "C" void kernel_launch(void* const* d_in, const int* in_sizes, int n_in,
                              void* d_out, int out_size, void* d_ws, size_t ws_size,
                              hipStream_t stream) {
    const float* data  = (const float*)d_in[0];
    const int*   label = (const int*)d_in[1];
    float*     out   = (float*)d_out;
    _Float16*  part  = (_Float16*)d_ws;                          // NBLK*3072 f16 (6.3 MB)
    float*     cpart = (float*)(part + (size_t)NBLK * KCH);      // NBLK*24 f32

    fm_main<<<dim3(NBLK), dim3(256), 0, stream>>>(data, label, part, cpart);
    fm_final<<<dim3(NB * NCLS * 2), dim3(256), 0, stream>>>(part, cpart, out);
}

// Round 17
// 25.900 us; speedup vs baseline: 1.0756x; 1.0756x over previous
//
#include <hip/hip_runtime.h>

#define NCLS 24
#define NB 8
#define NCH 128
#define WLO 128
#define WHI 512
#define CELLS (128*128)
#define BPB 128                     // blocks per batch (2 subtiles each)
#define NBLK (NB * BPB)             // 1024
#define KCH (NCLS * NCH)            // 3072
#define NF (NB * KCH)               // 24576

typedef _Float16 f16x4 __attribute__((ext_vector_type(4)));
typedef _Float16 f16x8 __attribute__((ext_vector_type(8)));
typedef float    f32x4 __attribute__((ext_vector_type(4)));
typedef int      i32x4 __attribute__((ext_vector_type(4)));

#define HSWZ(c_, e_) ((e_) ^ (((c_) & 7) << 3))

__device__ __forceinline__ void barrier_nodrain() {
    asm volatile("s_waitcnt lgkmcnt(0)" ::: "memory");
    __builtin_amdgcn_s_barrier();
}
// Counted VMEM wait + hard schedule fence (rule 18: fence AFTER the wait).
#define VMWAIT(N) do { asm volatile("s_waitcnt vmcnt(" #N ")" ::: "memory"); \
                       __builtin_amdgcn_sched_barrier(0); } while (0)

// Compiler-opaque loads: cannot be sunk/serialized; WE manage vmcnt.
__device__ __forceinline__ f32x4 gload_f4(const float* p) {
    f32x4 r;
    asm volatile("global_load_dwordx4 %0, %1, off" : "=v"(r) : "v"(p));
    return r;
}
__device__ __forceinline__ i32x4 gload_i4(const int* p) {
    i32x4 r;
    asm volatile("global_load_dwordx4 %0, %1, off" : "=v"(r) : "v"(p));
    return r;
}

// One block = one 128-cell row = 2 subtiles; acc carried in regs; hand-scheduled
// loads: 10 in flight at launch, 8 across the subtile-0 compute phase.
__global__ __launch_bounds__(256, 4)
void fm_main(const float* __restrict__ data, const int* __restrict__ label,
             _Float16* __restrict__ part, float* __restrict__ cpart)
{
    __shared__ float    histf[32 * 64];       // 8 KB, rows 24-31 stay zero
    __shared__ _Float16 tile[NCH * 64];       // 16 KB, [ch][cell swz]

    const int bid  = blockIdx.x;
    const int b    = bid >> 7;
    const int grp  = bid & 127;               // cell row
    const int tid  = threadIdx.x;

    const int q    = tid & 15;        // float4 slot (4 cells)
    const int chb  = tid >> 4;        // channel base 0..15
    const int cl   = tid & 63;        // label/hist cell
    const int w    = tid >> 6;        // wave id (= label hi-res row)
    const int lane = tid & 63;

    const float* dbase = data  + (size_t)b * NCH * CELLS + grp * WLO;
    const int*   lbase = label + (size_t)b * (WHI * WHI) + (size_t)(4 * grp + w) * WHI;

    // ---- issue: labels first (oldest), then subtile-0 data. 10 in flight. ----
    const i32x4 lv0 = gload_i4(lbase + cl * 4);
    const i32x4 lv1 = gload_i4(lbase + 256 + cl * 4);
    f32x4 v[8];
#pragma unroll
    for (int k = 0; k < 8; ++k)
        v[k] = gload_f4(dbase + (size_t)(chb + k * 16) * CELLS + q * 4);
    __builtin_amdgcn_sched_barrier(0);

    f32x4 acc[2][2];
#pragma unroll
    for (int mt = 0; mt < 2; ++mt)
#pragma unroll
        for (int nt = 0; nt < 2; ++nt) acc[mt][nt] = (f32x4){0.f, 0.f, 0.f, 0.f};
    float cs0 = 0.f, cs1 = 0.f;

    // ================= subtile 0 =================
#pragma unroll
    for (int k = 0; k < 8; ++k) histf[tid + k * 256] = 0.f;
    barrier_nodrain();

    VMWAIT(8);                                // lv0,lv1 landed; data still flying
    if ((unsigned)lv0[0] < 24u) atomicAdd(&histf[lv0[0] * 64 + HSWZ(lv0[0], cl)], 1.f);
    if ((unsigned)lv0[1] < 24u) atomicAdd(&histf[lv0[1] * 64 + HSWZ(lv0[1], cl)], 1.f);
    if ((unsigned)lv0[2] < 24u) atomicAdd(&histf[lv0[2] * 64 + HSWZ(lv0[2], cl)], 1.f);
    if ((unsigned)lv0[3] < 24u) atomicAdd(&histf[lv0[3] * 64 + HSWZ(lv0[3], cl)], 1.f);

    VMWAIT(0);                                // subtile-0 data landed
#pragma unroll
    for (int k = 0; k < 8; ++k) {
        const int ch = chb + k * 16;
        f16x4 hv;
        hv[0] = (_Float16)v[k][0]; hv[1] = (_Float16)v[k][1];
        hv[2] = (_Float16)v[k][2]; hv[3] = (_Float16)v[k][3];
        const int idx = ch * 64 + ((((q >> 1) ^ (ch & 7)) << 3) | ((q & 1) << 2));
        *reinterpret_cast<f16x4*>(&tile[idx]) = hv;
    }
    // ---- issue subtile-1 data NOW; drains only after MFMA-0 ----
#pragma unroll
    for (int k = 0; k < 8; ++k)
        v[k] = gload_f4(dbase + 64 + (size_t)(chb + k * 16) * CELLS + q * 4);
    __builtin_amdgcn_sched_barrier(0);
    barrier_nodrain();

#pragma unroll
    for (int s = 0; s < 2; ++s) {
        // ---- A fragments + count partials ----
        f16x8 af[2][2];
#pragma unroll
        for (int mt = 0; mt < 2; ++mt)
#pragma unroll
            for (int kt = 0; kt < 2; ++kt) {
                const int cls = mt * 16 + (lane & 15);
                const int e0  = kt * 32 + (lane >> 4) * 8;
                const float* hp = &histf[cls * 64 + HSWZ(cls, e0)];
                const f32x4 h0 = *reinterpret_cast<const f32x4*>(hp);
                const f32x4 h1 = *reinterpret_cast<const f32x4*>(hp + 4);
                f16x8 a;
                a[0] = (_Float16)h0[0]; a[1] = (_Float16)h0[1]; a[2] = (_Float16)h0[2]; a[3] = (_Float16)h0[3];
                a[4] = (_Float16)h1[0]; a[5] = (_Float16)h1[1]; a[6] = (_Float16)h1[2]; a[7] = (_Float16)h1[3];
                af[mt][kt] = a;
                const float p = (h0[0] + h0[1]) + (h0[2] + h0[3]) + (h1[0] + h1[1]) + (h1[2] + h1[3]);
                if (mt == 0) cs0 += p; else cs1 += p;
            }

        // ---- B fragments ----
        f16x8 bf[2][2];
#pragma unroll
        for (int nt = 0; nt < 2; ++nt)
#pragma unroll
            for (int kt = 0; kt < 2; ++kt) {
                const int row = w * 32 + nt * 16 + (lane & 15);
                const int g   = kt * 4 + (lane >> 4);
                bf[nt][kt] = *reinterpret_cast<const f16x8*>(&tile[row * 64 + ((g ^ (row & 7)) << 3)]);
            }

        // ---- 8 MFMAs ----
#pragma unroll
        for (int mt = 0; mt < 2; ++mt)
#pragma unroll
            for (int nt = 0; nt < 2; ++nt)
#pragma unroll
                for (int kt = 0; kt < 2; ++kt)
                    acc[mt][nt] = __builtin_amdgcn_mfma_f32_16x16x32_f16(
                        af[mt][kt], bf[nt][kt], acc[mt][nt], 0, 0, 0);

        if (s == 0) {
            // ---- transition to subtile 1: re-zero hist, atomics (lv1 in regs),
            //      then wait for prefetched data and stage ----
            barrier_nodrain();                // A/B-frag reads of s=0 retired
#pragma unroll
            for (int k = 0; k < 8; ++k) histf[tid + k * 256] = 0.f;
            barrier_nodrain();

            if ((unsigned)lv1[0] < 24u) atomicAdd(&histf[lv1[0] * 64 + HSWZ(lv1[0], cl)], 1.f);
            if ((unsigned)lv1[1] < 24u) atomicAdd(&histf[lv1[1] * 64 + HSWZ(lv1[1], cl)], 1.f);
            if ((unsigned)lv1[2] < 24u) atomicAdd(&histf[lv1[2] * 64 + HSWZ(lv1[2], cl)], 1.f);
            if ((unsigned)lv1[3] < 24u) atomicAdd(&histf[lv1[3] * 64 + HSWZ(lv1[3], cl)], 1.f);

            VMWAIT(0);                        // subtile-1 data landed
#pragma unroll
            for (int k = 0; k < 8; ++k) {
                const int ch = chb + k * 16;
                f16x4 hv;
                hv[0] = (_Float16)v[k][0]; hv[1] = (_Float16)v[k][1];
                hv[2] = (_Float16)v[k][2]; hv[3] = (_Float16)v[k][3];
                const int idx = ch * 64 + ((((q >> 1) ^ (ch & 7)) << 3) | ((q & 1) << 2));
                *reinterpret_cast<f16x4*>(&tile[idx]) = hv;
            }
            barrier_nodrain();
        }
    }

    // ---- counts: butterfly over 4 k-groups; wave 0 lanes write ----
    cs0 += __shfl_xor(cs0, 16, 64); cs0 += __shfl_xor(cs0, 32, 64);
    cs1 += __shfl_xor(cs1, 16, 64); cs1 += __shfl_xor(cs1, 32, 64);
    if (w == 0 && lane < 16) {
        cpart[(size_t)bid * NCLS + lane] = cs0;
        if (lane < 8) cpart[(size_t)bid * NCLS + 16 + lane] = cs1;
    }

    // ---- flush f16 per-block partials (non-atomic) ----
    _Float16* pblk = part + (size_t)bid * KCH;
#pragma unroll
    for (int mt = 0; mt < 2; ++mt)
#pragma unroll
        for (int nt = 0; nt < 2; ++nt)
#pragma unroll
            for (int rg = 0; rg < 4; ++rg) {
                const int cls = mt * 16 + (lane >> 4) * 4 + rg;   // C/D: row=(lane>>4)*4+reg
                const int ch  = w * 32 + nt * 16 + (lane & 15);   //      col=lane&15
                if (cls < NCLS) pblk[cls * NCH + ch] = (_Float16)acc[mt][nt][rg];
            }
}

// Grid 384 = (b, cls, ch-half). 4 waves reduce 32 g's each -> LDS -> wave-0 finish.
__global__ __launch_bounds__(256)
void fm_final(const _Float16* __restrict__ part, const float* __restrict__ cpart,
              float* __restrict__ out)
{
    __shared__ float red[256];
    __shared__ float credv[128];
    const int bid  = blockIdx.x;
    const int b    = bid / (NCLS * 2);
    const int rem  = bid % (NCLS * 2);
    const int cls  = rem >> 1;
    const int half = rem & 1;
    const int t    = threadIdx.x;
    const int c    = t & 63;
    const int gq   = t >> 6;

    if (t < 128) credv[t] = cpart[(size_t)(b * BPB + t) * NCLS + cls];

    const _Float16* pb = part + (size_t)(b * BPB + gq * 32) * KCH + cls * NCH + half * 64 + c;
    float s = 0.f;
#pragma unroll 8
    for (int g = 0; g < 32; ++g) s += (float)pb[(size_t)g * KCH];
    red[t] = s;
    __syncthreads();

    if (t < 64) {
        float cnt = credv[t] + credv[t + 64];
#pragma unroll
        for (int o = 32; o >= 1; o >>= 1) cnt += __shfl_xor(cnt, o, 64);
        const float sf = red[t] + red[t + 64] + red[t + 128] + red[t + 192];
        out[(size_t)b * KCH + (half * 64 + t) * NCLS + cls] = sf / (cnt + 1e-8f);  // (B,C,NCLS)
        if (t == 0 && half == 0) out[NF + b * NCLS + cls] = (cnt > 0.f) ? 1.f : 0.f;
    }
}

extern "C" void kernel_launch(void* const* d_in, const int* in_sizes, int n_in,
                              void* d_out, int out_size, void* d_ws, size_t ws_size,
                              hipStream_t stream) {
    const float* data  = (const float*)d_in[0];
    const int*   label = (const int*)d_in[1];
    float*     out   = (float*)d_out;
    _Float16*  part  = (_Float16*)d_ws;                          // NBLK*3072 f16 (6.3 MB)
    float*     cpart = (float*)(part + (size_t)NBLK * KCH);      // NBLK*24 f32

    fm_main<<<dim3(NBLK), dim3(256), 0, stream>>>(data, label, part, cpart);
    fm_final<<<dim3(NB * NCLS * 2), dim3(256), 0, stream>>>(part, cpart, out);
}